// Round 1
// baseline (1003.250 us; speedup 1.0000x reference)
//
#include <hip/hip_runtime.h>

#define NN 50000

// ---------------- edge dtype detection ----------------
// If edge_index arrived as int64 (little-endian, values < 50000), every odd
// 32-bit word of the first 4096 elements is 0. If int32, they are node ids
// (all-zero has ~0 probability). flag=1 -> int64.
__global__ void detect_kernel(const int* __restrict__ ei32, int* __restrict__ flag) {
    __shared__ int red[256];
    int tid = threadIdx.x;
    int o = 0;
    for (int i = tid; i < 4096; i += 256) o |= ei32[2 * i + 1];
    red[tid] = o;
    __syncthreads();
    for (int s = 128; s > 0; s >>= 1) {
        if (tid < s) red[tid] |= red[tid + s];
        __syncthreads();
    }
    if (tid == 0) *flag = (red[0] == 0) ? 1 : 0;
}

__device__ __forceinline__ int load_edge(const void* ei, int is64, long long idx) {
    return is64 ? (int)((const long long*)ei)[idx] : ((const int*)ei)[idx];
}

// ---------------- CSR build ----------------
__global__ void hist_kernel(const void* __restrict__ ei, const int* __restrict__ flag,
                            int* __restrict__ cnt, int E) {
    int e = blockIdx.x * blockDim.x + threadIdx.x;
    if (e >= E) return;
    int is64 = *flag;
    int dst = load_edge(ei, is64, (long long)E + e);
    atomicAdd(&cnt[dst], 1);
}

__global__ void scan_kernel(const int* __restrict__ cnt, int* __restrict__ off,
                            int* __restrict__ pos, int n) {
    const int T = 1024;
    __shared__ int s[T];
    int tid = threadIdx.x;
    int C = (n + T - 1) / T;
    int t0 = tid * C;
    int sum = 0;
    for (int j = 0; j < C; ++j) {
        int i = t0 + j;
        if (i < n) sum += cnt[i];
    }
    s[tid] = sum;
    __syncthreads();
    for (int o = 1; o < T; o <<= 1) {
        int v = 0;
        if (tid >= o) v = s[tid - o];
        __syncthreads();
        s[tid] += v;
        __syncthreads();
    }
    int run = s[tid] - sum;  // exclusive prefix of this thread's chunk
    for (int j = 0; j < C; ++j) {
        int i = t0 + j;
        if (i < n) {
            off[i] = run;
            pos[i] = run;
            run += cnt[i];
        }
    }
    if (tid == T - 1) off[n] = s[T - 1];
}

__global__ void fill_kernel(const void* __restrict__ ei, const int* __restrict__ flag,
                            int* __restrict__ pos, int* __restrict__ adj, int E) {
    int e = blockIdx.x * blockDim.x + threadIdx.x;
    if (e >= E) return;
    int is64 = *flag;
    int src = load_edge(ei, is64, e);
    int dst = load_edge(ei, is64, (long long)E + e);
    int p = atomicAdd(&pos[dst], 1);
    adj[p] = src;
}

// ---------------- mean aggregation (one node per block) ----------------
template <int F>
__global__ void agg_kernel(const float* __restrict__ feat, const int* __restrict__ off,
                           const int* __restrict__ adj, float* __restrict__ out) {
    int i = blockIdx.x;
    int f = threadIdx.x;
    int s = off[i], e = off[i + 1];
    float acc = 0.f;
    for (int j = s; j < e; ++j) {
        int src = adj[j];
        acc += feat[(size_t)src * F + f];
    }
    int deg = e - s;
    float d = deg > 0 ? (float)deg : 1.0f;
    out[(size_t)i * F + f] = acc / d;
}

// ---------------- fused SAGE GEMM: out = epilogue(agg@Wl + bl + x@Wr) ----------------
// 32 rows x 256 cols per block, 256 threads: thread = 8 rows x 4 contiguous cols.
// Each wave owns 8 full rows -> L2-norm is an in-wave shfl reduction.
template <int K, bool L0>
__global__ __launch_bounds__(256) void sage_gemm(
    const float* __restrict__ agg, const float* __restrict__ xin,
    const float* __restrict__ Wl, const float* __restrict__ bl,
    const float* __restrict__ Wr,
    const float* __restrict__ bng, const float* __restrict__ bnb,
    const float* __restrict__ bnm, const float* __restrict__ bnv,
    float* __restrict__ out, int n) {
    __shared__ float a_sh[32][K];
    __shared__ float x_sh[32][K];
    const int tid = threadIdx.x;
    const int row0 = blockIdx.x * 32;
    constexpr int KQ = K / 4;
    constexpr int VPT = (32 * KQ) / 256;
#pragma unroll
    for (int i = 0; i < VPT; ++i) {
        int v = tid + i * 256;
        int r = v / KQ;
        int kq = v - r * KQ;
        int row = row0 + r;
        float4 av = make_float4(0.f, 0.f, 0.f, 0.f);
        float4 xv = av;
        if (row < n) {
            av = *(const float4*)&agg[(size_t)row * K + kq * 4];
            xv = *(const float4*)&xin[(size_t)row * K + kq * 4];
        }
        *(float4*)&a_sh[r][kq * 4] = av;
        *(float4*)&x_sh[r][kq * 4] = xv;
    }
    __syncthreads();

    const int c = (tid & 63) * 4;       // 4 contiguous columns
    const int rg = (tid >> 6) * 8;      // wave id * 8 rows
    float acc[8][4] = {};
#pragma unroll 4
    for (int k = 0; k < K; ++k) {
        float4 wl = *(const float4*)&Wl[(size_t)k * 256 + c];
        float4 wr = *(const float4*)&Wr[(size_t)k * 256 + c];
#pragma unroll
        for (int r = 0; r < 8; ++r) {
            float a = a_sh[rg + r][k];
            float b = x_sh[rg + r][k];
            acc[r][0] += a * wl.x + b * wr.x;
            acc[r][1] += a * wl.y + b * wr.y;
            acc[r][2] += a * wl.z + b * wr.z;
            acc[r][3] += a * wl.w + b * wr.w;
        }
    }

    float4 bv = *(const float4*)&bl[c];
    float4 gm, be, mu, va;
    if (L0) {
        gm = *(const float4*)&bng[c];
        be = *(const float4*)&bnb[c];
        mu = *(const float4*)&bnm[c];
        va = *(const float4*)&bnv[c];
    }
#pragma unroll
    for (int r = 0; r < 8; ++r) {
        acc[r][0] += bv.x;
        acc[r][1] += bv.y;
        acc[r][2] += bv.z;
        acc[r][3] += bv.w;
        float ss = acc[r][0] * acc[r][0] + acc[r][1] * acc[r][1] +
                   acc[r][2] * acc[r][2] + acc[r][3] * acc[r][3];
#pragma unroll
        for (int o = 32; o > 0; o >>= 1) ss += __shfl_xor(ss, o, 64);
        float inv = 1.0f / fmaxf(sqrtf(ss), 1e-12f);
        float v0 = acc[r][0] * inv, v1 = acc[r][1] * inv;
        float v2 = acc[r][2] * inv, v3 = acc[r][3] * inv;
        if (L0) {
            float s0 = gm.x / sqrtf(va.x + 1e-5f);
            float s1 = gm.y / sqrtf(va.y + 1e-5f);
            float s2 = gm.z / sqrtf(va.z + 1e-5f);
            float s3 = gm.w / sqrtf(va.w + 1e-5f);
            v0 = fmaxf((v0 - mu.x) * s0 + be.x, 0.f);
            v1 = fmaxf((v1 - mu.y) * s1 + be.y, 0.f);
            v2 = fmaxf((v2 - mu.z) * s2 + be.z, 0.f);
            v3 = fmaxf((v3 - mu.w) * s3 + be.w, 0.f);
        }
        int row = row0 + rg + r;
        if (row < n)
            *(float4*)&out[(size_t)row * 256 + c] = make_float4(v0, v1, v2, v3);
    }
}

// ---------------- launch ----------------
extern "C" void kernel_launch(void* const* d_in, const int* in_sizes, int n_in,
                              void* d_out, int out_size, void* d_ws, size_t ws_size,
                              hipStream_t stream) {
    const float* x   = (const float*)d_in[0];
    const void*  ei  = d_in[1];
    const float* Wl0 = (const float*)d_in[2];
    const float* bl0 = (const float*)d_in[3];
    const float* Wr0 = (const float*)d_in[4];
    const float* Wl1 = (const float*)d_in[5];
    const float* bl1 = (const float*)d_in[6];
    const float* Wr1 = (const float*)d_in[7];
    const float* bng = (const float*)d_in[8];
    const float* bnb = (const float*)d_in[9];
    const float* bnm = (const float*)d_in[10];
    const float* bnv = (const float*)d_in[11];
    float* out = (float*)d_out;

    const int N = NN;
    const int E = in_sizes[1] / 2;

    // workspace carve (256B aligned)
    char* w = (char*)d_ws;
    size_t o = 0;
    auto carve = [&](size_t bytes) {
        void* p = w + o;
        o = (o + bytes + 255) & ~(size_t)255;
        return p;
    };
    int*   flag = (int*)carve(4);
    int*   cnt  = (int*)carve((size_t)N * 4);
    int*   off  = (int*)carve((size_t)(N + 1) * 4);
    int*   pos  = (int*)carve((size_t)N * 4);
    int*   adj  = (int*)carve((size_t)E * 4);
    float* agg  = (float*)carve((size_t)N * 256 * 4);

    // zero flag + cnt (contiguous from base)
    hipMemsetAsync(d_ws, 0, 256 + (size_t)N * 4, stream);

    detect_kernel<<<1, 256, 0, stream>>>((const int*)ei, flag);
    hist_kernel<<<(E + 255) / 256, 256, 0, stream>>>(ei, flag, cnt, E);
    scan_kernel<<<1, 1024, 0, stream>>>(cnt, off, pos, N);
    fill_kernel<<<(E + 255) / 256, 256, 0, stream>>>(ei, flag, pos, adj, E);

    // layer 0: aggregate x -> agg[.,128], then h (into d_out) = relu(bn(l2(agg@Wl0+b+x@Wr0)))
    agg_kernel<128><<<N, 128, 0, stream>>>(x, off, adj, agg);
    sage_gemm<128, true><<<(N + 31) / 32, 256, 0, stream>>>(
        agg, x, Wl0, bl0, Wr0, bng, bnb, bnm, bnv, out, N);

    // layer 1: aggregate h -> agg[.,256], then d_out = l2(agg@Wl1+b+h@Wr1)
    agg_kernel<256><<<N, 256, 0, stream>>>(out, off, adj, agg);
    sage_gemm<256, false><<<(N + 31) / 32, 256, 0, stream>>>(
        agg, out, Wl1, bl1, Wr1, bng, bnb, bnm, bnv, out, N);
}

// Round 2
// 428.901 us; speedup vs baseline: 2.3391x; 2.3391x over previous
//
#include <hip/hip_runtime.h>

#define NN 50000

typedef __bf16 bf16x8 __attribute__((ext_vector_type(8)));
typedef float f32x4 __attribute__((ext_vector_type(4)));

__device__ __forceinline__ unsigned short f2bf(float f) {
    unsigned int u = __builtin_bit_cast(unsigned int, f);
    u += 0x7FFF + ((u >> 16) & 1);  // round-to-nearest-even
    return (unsigned short)(u >> 16);
}
__device__ __forceinline__ float bf2f(unsigned short h) {
    unsigned int u = ((unsigned int)h) << 16;
    return __builtin_bit_cast(float, u);
}
__device__ __forceinline__ void gload16(const void* g, void* l) {
    __builtin_amdgcn_global_load_lds(
        (const __attribute__((address_space(1))) unsigned int*)g,
        (__attribute__((address_space(3))) unsigned int*)l, 16, 0, 0);
}

// ---------------- edge dtype detection ----------------
__global__ void detect_kernel(const int* __restrict__ ei32, int* __restrict__ flag) {
    __shared__ int red[256];
    int tid = threadIdx.x;
    int o = 0;
    for (int i = tid; i < 4096; i += 256) o |= ei32[2 * i + 1];
    red[tid] = o;
    __syncthreads();
    for (int s = 128; s > 0; s >>= 1) {
        if (tid < s) red[tid] |= red[tid + s];
        __syncthreads();
    }
    if (tid == 0) *flag = (red[0] == 0) ? 1 : 0;
}

__device__ __forceinline__ int load_edge(const void* ei, int is64, long long idx) {
    return is64 ? (int)((const long long*)ei)[idx] : ((const int*)ei)[idx];
}

// ---------------- CSR build ----------------
__global__ void hist_kernel(const void* __restrict__ ei, const int* __restrict__ flag,
                            int* __restrict__ cnt, int E) {
    int e = blockIdx.x * blockDim.x + threadIdx.x;
    if (e >= E) return;
    int is64 = *flag;
    int dst = load_edge(ei, is64, (long long)E + e);
    atomicAdd(&cnt[dst], 1);
}

__global__ void scan_kernel(const int* __restrict__ cnt, int* __restrict__ off,
                            int* __restrict__ pos, int n) {
    const int T = 1024;
    __shared__ int s[T];
    int tid = threadIdx.x;
    int C = (n + T - 1) / T;
    int t0 = tid * C;
    int sum = 0;
    for (int j = 0; j < C; ++j) {
        int i = t0 + j;
        if (i < n) sum += cnt[i];
    }
    s[tid] = sum;
    __syncthreads();
    for (int o = 1; o < T; o <<= 1) {
        int v = 0;
        if (tid >= o) v = s[tid - o];
        __syncthreads();
        s[tid] += v;
        __syncthreads();
    }
    int run = s[tid] - sum;
    for (int j = 0; j < C; ++j) {
        int i = t0 + j;
        if (i < n) {
            off[i] = run;
            pos[i] = run;
            run += cnt[i];
        }
    }
    if (tid == T - 1) off[n] = s[T - 1];
}

__global__ void fill_kernel(const void* __restrict__ ei, const int* __restrict__ flag,
                            int* __restrict__ pos, int* __restrict__ adj, int E) {
    int e = blockIdx.x * blockDim.x + threadIdx.x;
    if (e >= E) return;
    int is64 = *flag;
    int src = load_edge(ei, is64, e);
    int dst = load_edge(ei, is64, (long long)E + e);
    int p = atomicAdd(&pos[dst], 1);
    adj[p] = src;
}

// ---------------- f32 -> bf16 convert ----------------
__global__ void cvt_bf16(const float* __restrict__ in, unsigned short* __restrict__ out, int n4) {
    int i = blockIdx.x * blockDim.x + threadIdx.x;
    if (i >= n4) return;
    float4 v = ((const float4*)in)[i];
    uint2 o;
    o.x = (unsigned int)f2bf(v.x) | ((unsigned int)f2bf(v.y) << 16);
    o.y = (unsigned int)f2bf(v.z) | ((unsigned int)f2bf(v.w) << 16);
    ((uint2*)out)[i] = o;
}

// ---------------- weight prep: Wt[c][k] = bf16([Wl; Wr][k][c]) ----------------
__global__ void prep_w(const float* __restrict__ Wl, const float* __restrict__ Wr,
                       unsigned short* __restrict__ Wt, int KH) {
    int c = blockIdx.x;  // 0..255
    int KC = 2 * KH;
    for (int k = threadIdx.x; k < KC; k += blockDim.x) {
        float v = (k < KH) ? Wl[(size_t)k * 256 + c] : Wr[(size_t)(k - KH) * 256 + c];
        Wt[(size_t)c * KC + k] = f2bf(v);
    }
}

// ---------------- mean aggregation, bf16 in/out, one wave per node ----------------
template <int VPL>  // values per lane; F = 64*VPL
__global__ void agg_bf(const unsigned short* __restrict__ feat, const int* __restrict__ off,
                       const int* __restrict__ adj, unsigned short* __restrict__ out, int n) {
    int node = blockIdx.x * 4 + (threadIdx.x >> 6);
    if (node >= n) return;
    const int lane = threadIdx.x & 63;
    constexpr int F = 64 * VPL;
    const int s = off[node], e = off[node + 1];
    float acc[VPL] = {};
    for (int j = s; j < e; ++j) {
        int src = adj[j];
        const unsigned short* p = feat + (size_t)src * F + lane * VPL;
        if constexpr (VPL == 2) {
            unsigned int v = *(const unsigned int*)p;
            acc[0] += bf2f((unsigned short)(v & 0xffff));
            acc[1] += bf2f((unsigned short)(v >> 16));
        } else {
            uint2 v = *(const uint2*)p;
            acc[0] += bf2f((unsigned short)(v.x & 0xffff));
            acc[1] += bf2f((unsigned short)(v.x >> 16));
            acc[2] += bf2f((unsigned short)(v.y & 0xffff));
            acc[3] += bf2f((unsigned short)(v.y >> 16));
        }
    }
    int deg = e - s;
    float inv = 1.0f / (float)(deg > 0 ? deg : 1);
    if constexpr (VPL == 2) {
        unsigned int o = (unsigned int)f2bf(acc[0] * inv) | ((unsigned int)f2bf(acc[1] * inv) << 16);
        *(unsigned int*)(out + (size_t)node * F + lane * 2) = o;
    } else {
        uint2 o;
        o.x = (unsigned int)f2bf(acc[0] * inv) | ((unsigned int)f2bf(acc[1] * inv) << 16);
        o.y = (unsigned int)f2bf(acc[2] * inv) | ((unsigned int)f2bf(acc[3] * inv) << 16);
        *(uint2*)(out + (size_t)node * F + lane * 4) = o;
    }
}

// ---------------- fused SAGE MFMA GEMM ----------------
// C[64 x 256] per block = [agg | xin](64 x 2KH) @ Wt^T, 4 waves, wave w owns cols [64w,64w+64).
// A staged via global_load_lds into [kgroup][row][8] (linear per-lane), double-buffered.
// Epilogue: +bias, L2-normalize rows (shfl + LDS cross-wave), optional BN+ReLU, store.
template <int KH, bool L0>
__global__ __launch_bounds__(256, 2) void sage_mfma(
    const unsigned short* __restrict__ Aagg, const unsigned short* __restrict__ Axin,
    const unsigned short* __restrict__ Wt, const float* __restrict__ bl,
    const float* __restrict__ bng, const float* __restrict__ bnb,
    const float* __restrict__ bnm, const float* __restrict__ bnv,
    unsigned short* __restrict__ hout, float* __restrict__ fout, int n) {
    constexpr int KC = 2 * KH;
    constexpr int NSTEP = KC / 32;
    __shared__ __align__(16) unsigned short a_sh[2][4][64][8];  // [buf][kgrp][row][8] = 8KB
    __shared__ float red[4][64];
    __shared__ float inv_sh[64];

    const int tid = threadIdx.x;
    const int w = tid >> 6;
    const int l = tid & 63;
    const int g = l >> 4;
    const int li = l & 15;
    const int row0 = blockIdx.x * 64;
    int srow = row0 + l;
    if (srow >= n) srow = n - 1;

    f32x4 acc[4][4];
#pragma unroll
    for (int m = 0; m < 4; ++m)
#pragma unroll
        for (int nn = 0; nn < 4; ++nn) acc[m][nn] = (f32x4)(0.0f);

    auto stage = [&](int buf, int t) {
        const int k0 = t * 32;
        const unsigned short* srcm = (k0 < KH) ? Aagg : Axin;
        const int kk = (k0 < KH) ? k0 : k0 - KH;
        const unsigned short* gp = srcm + (size_t)srow * KH + kk + w * 8;
        gload16(gp, &a_sh[buf][w][0][0]);  // lane i -> a_sh[buf][w][i][0..7]
    };

    stage(0, 0);
    __syncthreads();  // vmcnt(0) drain + barrier: buf0 ready

    int cur = 0;
    for (int ks = 0; ks < NSTEP; ++ks) {
        if (ks + 1 < NSTEP) stage(cur ^ 1, ks + 1);  // prefetch in flight during compute
        const int k0 = ks * 32;
        bf16x8 bfr[4];
#pragma unroll
        for (int nn = 0; nn < 4; ++nn) {
            const unsigned short* bp = Wt + (size_t)(w * 64 + nn * 16 + li) * KC + k0 + 8 * g;
            bfr[nn] = __builtin_bit_cast(bf16x8, *(const uint4*)bp);
        }
        bf16x8 afr[4];
#pragma unroll
        for (int m = 0; m < 4; ++m)
            afr[m] = __builtin_bit_cast(bf16x8, *(const uint4*)&a_sh[cur][g][16 * m + li][0]);
#pragma unroll
        for (int nn = 0; nn < 4; ++nn)
#pragma unroll
            for (int m = 0; m < 4; ++m)
                acc[m][nn] = __builtin_amdgcn_mfma_f32_16x16x32_bf16(afr[m], bfr[nn], acc[m][nn], 0, 0, 0);
        __syncthreads();  // drains prefetch vmcnt + guards buffer swap
        cur ^= 1;
    }

    // bias
    float bv[4];
#pragma unroll
    for (int nn = 0; nn < 4; ++nn) bv[nn] = bl[w * 64 + nn * 16 + li];
#pragma unroll
    for (int m = 0; m < 4; ++m)
#pragma unroll
        for (int nn = 0; nn < 4; ++nn)
#pragma unroll
            for (int r = 0; r < 4; ++r) acc[m][nn][r] += bv[nn];

    // row sum-of-squares: reduce over this wave's 64 cols (16-lane group shuffle)
    float ssp[4][4];
#pragma unroll
    for (int m = 0; m < 4; ++m)
#pragma unroll
        for (int r = 0; r < 4; ++r) {
            float s = 0.f;
#pragma unroll
            for (int nn = 0; nn < 4; ++nn) s += acc[m][nn][r] * acc[m][nn][r];
#pragma unroll
            for (int mk = 1; mk < 16; mk <<= 1) s += __shfl_xor(s, mk, 64);
            ssp[m][r] = s;
        }
    if (li == 0) {
#pragma unroll
        for (int m = 0; m < 4; ++m)
#pragma unroll
            for (int r = 0; r < 4; ++r) red[w][16 * m + 4 * g + r] = ssp[m][r];
    }
    __syncthreads();
    if (tid < 64) {
        float tot = red[0][tid] + red[1][tid] + red[2][tid] + red[3][tid];
        inv_sh[tid] = 1.0f / fmaxf(sqrtf(tot), 1e-12f);
    }
    __syncthreads();

    float sc[4], sh[4];
    if (L0) {
#pragma unroll
        for (int nn = 0; nn < 4; ++nn) {
            int c = w * 64 + nn * 16 + li;
            float s = bng[c] * rsqrtf(bnv[c] + 1e-5f);
            sc[nn] = s;
            sh[nn] = bnb[c] - bnm[c] * s;
        }
    }
#pragma unroll
    for (int m = 0; m < 4; ++m) {
#pragma unroll
        for (int r = 0; r < 4; ++r) {
            int rl = 16 * m + 4 * g + r;
            int row = row0 + rl;
            if (row < n) {
                float inv = inv_sh[rl];
#pragma unroll
                for (int nn = 0; nn < 4; ++nn) {
                    int c = w * 64 + nn * 16 + li;
                    float v = acc[m][nn][r] * inv;
                    if (L0) {
                        v = fmaxf(v * sc[nn] + sh[nn], 0.f);
                        hout[(size_t)row * 256 + c] = f2bf(v);
                    } else {
                        fout[(size_t)row * 256 + c] = v;
                    }
                }
            }
        }
    }
}

// ---------------- launch ----------------
extern "C" void kernel_launch(void* const* d_in, const int* in_sizes, int n_in,
                              void* d_out, int out_size, void* d_ws, size_t ws_size,
                              hipStream_t stream) {
    const float* x   = (const float*)d_in[0];
    const void*  ei  = d_in[1];
    const float* Wl0 = (const float*)d_in[2];
    const float* bl0 = (const float*)d_in[3];
    const float* Wr0 = (const float*)d_in[4];
    const float* Wl1 = (const float*)d_in[5];
    const float* bl1 = (const float*)d_in[6];
    const float* Wr1 = (const float*)d_in[7];
    const float* bng = (const float*)d_in[8];
    const float* bnb = (const float*)d_in[9];
    const float* bnm = (const float*)d_in[10];
    const float* bnv = (const float*)d_in[11];
    float* out = (float*)d_out;

    const int N = NN;
    const int E = in_sizes[1] / 2;

    char* wsp = (char*)d_ws;
    size_t o = 0;
    auto carve = [&](size_t bytes) {
        void* p = wsp + o;
        o = (o + bytes + 255) & ~(size_t)255;
        return p;
    };
    int* flag = (int*)carve(4);
    int* cnt  = (int*)carve((size_t)N * 4);
    int* off  = (int*)carve((size_t)(N + 1) * 4);
    int* pos  = (int*)carve((size_t)N * 4);
    int* adj  = (int*)carve((size_t)E * 4);
    unsigned short* xbf  = (unsigned short*)carve((size_t)N * 128 * 2);
    unsigned short* agg0 = (unsigned short*)carve((size_t)N * 128 * 2);
    unsigned short* agg1 = xbf;  // reuse xbf+agg0 region (dead after layer 0)
    unsigned short* hbf  = (unsigned short*)carve((size_t)N * 256 * 2);
    unsigned short* Wt0  = (unsigned short*)carve((size_t)256 * 256 * 2);
    unsigned short* Wt1  = (unsigned short*)carve((size_t)256 * 512 * 2);

    hipMemsetAsync(d_ws, 0, 256 + (size_t)N * 4, stream);

    detect_kernel<<<1, 256, 0, stream>>>((const int*)ei, flag);
    hist_kernel<<<(E + 255) / 256, 256, 0, stream>>>(ei, flag, cnt, E);
    scan_kernel<<<1, 1024, 0, stream>>>(cnt, off, pos, N);
    fill_kernel<<<(E + 255) / 256, 256, 0, stream>>>(ei, flag, pos, adj, E);

    cvt_bf16<<<(N * 128 / 4 + 255) / 256, 256, 0, stream>>>(x, xbf, N * 128 / 4);
    prep_w<<<256, 256, 0, stream>>>(Wl0, Wr0, Wt0, 128);
    prep_w<<<256, 256, 0, stream>>>(Wl1, Wr1, Wt1, 256);

    agg_bf<2><<<(N + 3) / 4, 256, 0, stream>>>(xbf, off, adj, agg0, N);
    sage_mfma<128, true><<<(N + 63) / 64, 256, 0, stream>>>(
        agg0, xbf, Wt0, bl0, bng, bnb, bnm, bnv, hbf, nullptr, N);

    agg_bf<4><<<(N + 3) / 4, 256, 0, stream>>>(hbf, off, adj, agg1, N);
    sage_mfma<256, false><<<(N + 63) / 64, 256, 0, stream>>>(
        agg1, hbf, Wt1, bl1, bng, bnb, bnm, bnv, nullptr, out, N);
}

// Round 3
// 310.868 us; speedup vs baseline: 3.2273x; 1.3797x over previous
//
#include <hip/hip_runtime.h>

#define NN 50000

typedef __bf16 bf16x8 __attribute__((ext_vector_type(8)));
typedef float f32x4 __attribute__((ext_vector_type(4)));

__device__ __forceinline__ unsigned short f2bf(float f) {
    unsigned int u = __builtin_bit_cast(unsigned int, f);
    u += 0x7FFF + ((u >> 16) & 1);  // round-to-nearest-even
    return (unsigned short)(u >> 16);
}
__device__ __forceinline__ float bf2f(unsigned short h) {
    unsigned int u = ((unsigned int)h) << 16;
    return __builtin_bit_cast(float, u);
}
__device__ __forceinline__ void gload16(const void* g, void* l) {
    __builtin_amdgcn_global_load_lds(
        (const __attribute__((address_space(1))) unsigned int*)g,
        (__attribute__((address_space(3))) unsigned int*)l, 16, 0, 0);
}

// ---------------- edge dtype detection ----------------
__global__ void detect_kernel(const int* __restrict__ ei32, int* __restrict__ flag) {
    __shared__ int red[256];
    int tid = threadIdx.x;
    int o = 0;
    for (int i = tid; i < 4096; i += 256) o |= ei32[2 * i + 1];
    red[tid] = o;
    __syncthreads();
    for (int s = 128; s > 0; s >>= 1) {
        if (tid < s) red[tid] |= red[tid + s];
        __syncthreads();
    }
    if (tid == 0) *flag = (red[0] == 0) ? 1 : 0;
}

__device__ __forceinline__ int load_edge(const void* ei, int is64, long long idx) {
    return is64 ? (int)((const long long*)ei)[idx] : ((const int*)ei)[idx];
}

// ---------------- CSR build ----------------
__global__ void hist_kernel(const void* __restrict__ ei, const int* __restrict__ flag,
                            int* __restrict__ cnt, int E) {
    int e = blockIdx.x * blockDim.x + threadIdx.x;
    if (e >= E) return;
    int is64 = *flag;
    int dst = load_edge(ei, is64, (long long)E + e);
    atomicAdd(&cnt[dst], 1);
}

// pass 1: block b reduces cnt[b*1024 .. b*1024+1023] -> bsum[b]
__global__ void scan_part(const int* __restrict__ cnt, int* __restrict__ bsum, int n) {
    __shared__ int s[256];
    const int tid = threadIdx.x;
    const int i0 = blockIdx.x * 1024 + tid * 4;
    int sum = 0;
#pragma unroll
    for (int j = 0; j < 4; ++j) {
        int i = i0 + j;
        if (i < n) sum += cnt[i];
    }
    s[tid] = sum;
    __syncthreads();
    for (int o = 128; o > 0; o >>= 1) {
        if (tid < o) s[tid] += s[tid + o];
        __syncthreads();
    }
    if (tid == 0) bsum[blockIdx.x] = s[0];
}

// pass 2: one wave turns bsum[] (nb <= 64) into its exclusive scan; off[n] = total
__global__ void scan_top(int* __restrict__ bsum, int* __restrict__ off, int nb, int n) {
    const int lane = threadIdx.x & 63;
    int mine = (lane < nb) ? bsum[lane] : 0;
    int v = mine;
#pragma unroll
    for (int o = 1; o < 64; o <<= 1) {
        int t = __shfl_up(v, o, 64);
        if (lane >= o) v += t;
    }
    if (lane < nb) bsum[lane] = v - mine;  // exclusive prefix
    if (lane == 63) off[n] = v;            // grand total
}

// pass 3: block b scans its 1024 counts with base bsum[b]; writes off/pos
__global__ void scan_fin(const int* __restrict__ cnt, const int* __restrict__ bsum,
                         int* __restrict__ off, int* __restrict__ pos, int n) {
    __shared__ int s[256];
    const int tid = threadIdx.x;
    const int i0 = blockIdx.x * 1024 + tid * 4;
    int v[4];
    int sum = 0;
#pragma unroll
    for (int j = 0; j < 4; ++j) {
        int i = i0 + j;
        v[j] = (i < n) ? cnt[i] : 0;
        sum += v[j];
    }
    s[tid] = sum;
    __syncthreads();
    for (int o = 1; o < 256; o <<= 1) {
        int t = 0;
        if (tid >= o) t = s[tid - o];
        __syncthreads();
        s[tid] += t;
        __syncthreads();
    }
    int run = bsum[blockIdx.x] + s[tid] - sum;  // exclusive within grid
#pragma unroll
    for (int j = 0; j < 4; ++j) {
        int i = i0 + j;
        if (i < n) {
            off[i] = run;
            pos[i] = run;
            run += v[j];
        }
    }
}

__global__ void fill_kernel(const void* __restrict__ ei, const int* __restrict__ flag,
                            int* __restrict__ pos, int* __restrict__ adj, int E) {
    int e = blockIdx.x * blockDim.x + threadIdx.x;
    if (e >= E) return;
    int is64 = *flag;
    int src = load_edge(ei, is64, e);
    int dst = load_edge(ei, is64, (long long)E + e);
    int p = atomicAdd(&pos[dst], 1);
    adj[p] = src;
}

// ---------------- f32 -> bf16 convert ----------------
__global__ void cvt_bf16(const float* __restrict__ in, unsigned short* __restrict__ out, int n4) {
    int i = blockIdx.x * blockDim.x + threadIdx.x;
    if (i >= n4) return;
    float4 v = ((const float4*)in)[i];
    uint2 o;
    o.x = (unsigned int)f2bf(v.x) | ((unsigned int)f2bf(v.y) << 16);
    o.y = (unsigned int)f2bf(v.z) | ((unsigned int)f2bf(v.w) << 16);
    ((uint2*)out)[i] = o;
}

// ---------------- weight prep: Wt[c][k] = bf16([Wl; Wr][k][c]) ----------------
__global__ void prep_w(const float* __restrict__ Wl, const float* __restrict__ Wr,
                       unsigned short* __restrict__ Wt, int KH) {
    int c = blockIdx.x;  // 0..255
    int KC = 2 * KH;
    for (int k = threadIdx.x; k < KC; k += blockDim.x) {
        float v = (k < KH) ? Wl[(size_t)k * 256 + c] : Wr[(size_t)(k - KH) * 256 + c];
        Wt[(size_t)c * KC + k] = f2bf(v);
    }
}

// ---------------- mean aggregation, bf16 in/out, one wave per node ----------------
template <int VPL>  // values per lane; F = 64*VPL
__global__ void agg_bf(const unsigned short* __restrict__ feat, const int* __restrict__ off,
                       const int* __restrict__ adj, unsigned short* __restrict__ out, int n) {
    int node = blockIdx.x * 4 + (threadIdx.x >> 6);
    if (node >= n) return;
    const int lane = threadIdx.x & 63;
    constexpr int F = 64 * VPL;
    const int s = off[node], e = off[node + 1];
    float acc[VPL] = {};
    for (int j = s; j < e; ++j) {
        int src = adj[j];
        const unsigned short* p = feat + (size_t)src * F + lane * VPL;
        if constexpr (VPL == 2) {
            unsigned int v = *(const unsigned int*)p;
            acc[0] += bf2f((unsigned short)(v & 0xffff));
            acc[1] += bf2f((unsigned short)(v >> 16));
        } else {
            uint2 v = *(const uint2*)p;
            acc[0] += bf2f((unsigned short)(v.x & 0xffff));
            acc[1] += bf2f((unsigned short)(v.x >> 16));
            acc[2] += bf2f((unsigned short)(v.y & 0xffff));
            acc[3] += bf2f((unsigned short)(v.y >> 16));
        }
    }
    int deg = e - s;
    float inv = 1.0f / (float)(deg > 0 ? deg : 1);
    if constexpr (VPL == 2) {
        unsigned int o = (unsigned int)f2bf(acc[0] * inv) | ((unsigned int)f2bf(acc[1] * inv) << 16);
        *(unsigned int*)(out + (size_t)node * F + lane * 2) = o;
    } else {
        uint2 o;
        o.x = (unsigned int)f2bf(acc[0] * inv) | ((unsigned int)f2bf(acc[1] * inv) << 16);
        o.y = (unsigned int)f2bf(acc[2] * inv) | ((unsigned int)f2bf(acc[3] * inv) << 16);
        *(uint2*)(out + (size_t)node * F + lane * 4) = o;
    }
}

// ---------------- fused SAGE MFMA GEMM ----------------
// C[64 x 256] per block = [agg | xin](64 x 2KH) @ Wt^T, 4 waves, wave w owns cols [64w,64w+64).
// A staged via global_load_lds into [kgroup][row][8] (linear per-lane), double-buffered.
// Epilogue: +bias, L2-normalize rows (shfl + LDS cross-wave), optional BN+ReLU, store.
template <int KH, bool L0>
__global__ __launch_bounds__(256, 2) void sage_mfma(
    const unsigned short* __restrict__ Aagg, const unsigned short* __restrict__ Axin,
    const unsigned short* __restrict__ Wt, const float* __restrict__ bl,
    const float* __restrict__ bng, const float* __restrict__ bnb,
    const float* __restrict__ bnm, const float* __restrict__ bnv,
    unsigned short* __restrict__ hout, float* __restrict__ fout, int n) {
    constexpr int KC = 2 * KH;
    constexpr int NSTEP = KC / 32;
    __shared__ __align__(16) unsigned short a_sh[2][4][64][8];  // [buf][kgrp][row][8] = 8KB
    __shared__ float red[4][64];
    __shared__ float inv_sh[64];

    const int tid = threadIdx.x;
    const int w = tid >> 6;
    const int l = tid & 63;
    const int g = l >> 4;
    const int li = l & 15;
    const int row0 = blockIdx.x * 64;
    int srow = row0 + l;
    if (srow >= n) srow = n - 1;

    f32x4 acc[4][4];
#pragma unroll
    for (int m = 0; m < 4; ++m)
#pragma unroll
        for (int nn = 0; nn < 4; ++nn) acc[m][nn] = (f32x4)(0.0f);

    auto stage = [&](int buf, int t) {
        const int k0 = t * 32;
        const unsigned short* srcm = (k0 < KH) ? Aagg : Axin;
        const int kk = (k0 < KH) ? k0 : k0 - KH;
        const unsigned short* gp = srcm + (size_t)srow * KH + kk + w * 8;
        gload16(gp, &a_sh[buf][w][0][0]);  // lane i -> a_sh[buf][w][i][0..7]
    };

    stage(0, 0);
    __syncthreads();  // vmcnt(0) drain + barrier: buf0 ready

    int cur = 0;
    for (int ks = 0; ks < NSTEP; ++ks) {
        if (ks + 1 < NSTEP) stage(cur ^ 1, ks + 1);  // prefetch in flight during compute
        const int k0 = ks * 32;
        bf16x8 bfr[4];
#pragma unroll
        for (int nn = 0; nn < 4; ++nn) {
            const unsigned short* bp = Wt + (size_t)(w * 64 + nn * 16 + li) * KC + k0 + 8 * g;
            bfr[nn] = __builtin_bit_cast(bf16x8, *(const uint4*)bp);
        }
        bf16x8 afr[4];
#pragma unroll
        for (int m = 0; m < 4; ++m)
            afr[m] = __builtin_bit_cast(bf16x8, *(const uint4*)&a_sh[cur][g][16 * m + li][0]);
#pragma unroll
        for (int nn = 0; nn < 4; ++nn)
#pragma unroll
            for (int m = 0; m < 4; ++m)
                acc[m][nn] = __builtin_amdgcn_mfma_f32_16x16x32_bf16(afr[m], bfr[nn], acc[m][nn], 0, 0, 0);
        __syncthreads();  // drains prefetch vmcnt + guards buffer swap
        cur ^= 1;
    }

    // bias
    float bv[4];
#pragma unroll
    for (int nn = 0; nn < 4; ++nn) bv[nn] = bl[w * 64 + nn * 16 + li];
#pragma unroll
    for (int m = 0; m < 4; ++m)
#pragma unroll
        for (int nn = 0; nn < 4; ++nn)
#pragma unroll
            for (int r = 0; r < 4; ++r) acc[m][nn][r] += bv[nn];

    // row sum-of-squares: reduce over this wave's 64 cols (16-lane group shuffle)
    float ssp[4][4];
#pragma unroll
    for (int m = 0; m < 4; ++m)
#pragma unroll
        for (int r = 0; r < 4; ++r) {
            float s = 0.f;
#pragma unroll
            for (int nn = 0; nn < 4; ++nn) s += acc[m][nn][r] * acc[m][nn][r];
#pragma unroll
            for (int mk = 1; mk < 16; mk <<= 1) s += __shfl_xor(s, mk, 64);
            ssp[m][r] = s;
        }
    if (li == 0) {
#pragma unroll
        for (int m = 0; m < 4; ++m)
#pragma unroll
            for (int r = 0; r < 4; ++r) red[w][16 * m + 4 * g + r] = ssp[m][r];
    }
    __syncthreads();
    if (tid < 64) {
        float tot = red[0][tid] + red[1][tid] + red[2][tid] + red[3][tid];
        inv_sh[tid] = 1.0f / fmaxf(sqrtf(tot), 1e-12f);
    }
    __syncthreads();

    float sc[4], sh[4];
    if (L0) {
#pragma unroll
        for (int nn = 0; nn < 4; ++nn) {
            int c = w * 64 + nn * 16 + li;
            float s = bng[c] * rsqrtf(bnv[c] + 1e-5f);
            sc[nn] = s;
            sh[nn] = bnb[c] - bnm[c] * s;
        }
    }
#pragma unroll
    for (int m = 0; m < 4; ++m) {
#pragma unroll
        for (int r = 0; r < 4; ++r) {
            int rl = 16 * m + 4 * g + r;
            int row = row0 + rl;
            if (row < n) {
                float inv = inv_sh[rl];
#pragma unroll
                for (int nn = 0; nn < 4; ++nn) {
                    int c = w * 64 + nn * 16 + li;
                    float v = acc[m][nn][r] * inv;
                    if (L0) {
                        v = fmaxf(v * sc[nn] + sh[nn], 0.f);
                        hout[(size_t)row * 256 + c] = f2bf(v);
                    } else {
                        fout[(size_t)row * 256 + c] = v;
                    }
                }
            }
        }
    }
}

// ---------------- launch ----------------
extern "C" void kernel_launch(void* const* d_in, const int* in_sizes, int n_in,
                              void* d_out, int out_size, void* d_ws, size_t ws_size,
                              hipStream_t stream) {
    const float* x   = (const float*)d_in[0];
    const void*  ei  = d_in[1];
    const float* Wl0 = (const float*)d_in[2];
    const float* bl0 = (const float*)d_in[3];
    const float* Wr0 = (const float*)d_in[4];
    const float* Wl1 = (const float*)d_in[5];
    const float* bl1 = (const float*)d_in[6];
    const float* Wr1 = (const float*)d_in[7];
    const float* bng = (const float*)d_in[8];
    const float* bnb = (const float*)d_in[9];
    const float* bnm = (const float*)d_in[10];
    const float* bnv = (const float*)d_in[11];
    float* out = (float*)d_out;

    const int N = NN;
    const int E = in_sizes[1] / 2;
    const int NB = (N + 1023) / 1024;  // 49 scan blocks

    char* wsp = (char*)d_ws;
    size_t o = 0;
    auto carve = [&](size_t bytes) {
        void* p = wsp + o;
        o = (o + bytes + 255) & ~(size_t)255;
        return p;
    };
    int* flag = (int*)carve(4);
    int* cnt  = (int*)carve((size_t)N * 4);
    int* off  = (int*)carve((size_t)(N + 1) * 4);
    int* pos  = (int*)carve((size_t)N * 4);
    int* bsum = (int*)carve((size_t)NB * 4);
    int* adj  = (int*)carve((size_t)E * 4);
    unsigned short* xbf  = (unsigned short*)carve((size_t)N * 128 * 2);
    unsigned short* agg0 = (unsigned short*)carve((size_t)N * 128 * 2);
    unsigned short* agg1 = xbf;  // reuse xbf region (dead after layer 0)
    unsigned short* hbf  = (unsigned short*)carve((size_t)N * 256 * 2);
    unsigned short* Wt0  = (unsigned short*)carve((size_t)256 * 256 * 2);
    unsigned short* Wt1  = (unsigned short*)carve((size_t)256 * 512 * 2);

    hipMemsetAsync(d_ws, 0, 256 + (size_t)N * 4, stream);

    detect_kernel<<<1, 256, 0, stream>>>((const int*)ei, flag);
    hist_kernel<<<(E + 255) / 256, 256, 0, stream>>>(ei, flag, cnt, E);
    scan_part<<<NB, 256, 0, stream>>>(cnt, bsum, N);
    scan_top<<<1, 64, 0, stream>>>(bsum, off, NB, N);
    scan_fin<<<NB, 256, 0, stream>>>(cnt, bsum, off, pos, N);
    fill_kernel<<<(E + 255) / 256, 256, 0, stream>>>(ei, flag, pos, adj, E);

    cvt_bf16<<<(N * 128 / 4 + 255) / 256, 256, 0, stream>>>(x, xbf, N * 128 / 4);
    prep_w<<<256, 256, 0, stream>>>(Wl0, Wr0, Wt0, 128);
    prep_w<<<256, 256, 0, stream>>>(Wl1, Wr1, Wt1, 256);

    agg_bf<2><<<(N + 3) / 4, 256, 0, stream>>>(xbf, off, adj, agg0, N);
    sage_mfma<128, true><<<(N + 63) / 64, 256, 0, stream>>>(
        agg0, xbf, Wt0, bl0, bng, bnb, bnm, bnv, hbf, nullptr, N);

    agg_bf<4><<<(N + 3) / 4, 256, 0, stream>>>(hbf, off, adj, agg1, N);
    sage_mfma<256, false><<<(N + 63) / 64, 256, 0, stream>>>(
        agg1, hbf, Wt1, bl1, bng, bnb, bnm, bnv, nullptr, out, N);
}

// Round 4
// 252.430 us; speedup vs baseline: 3.9744x; 1.2315x over previous
//
#include <hip/hip_runtime.h>

#define NN 50000

typedef __bf16 bf16x8 __attribute__((ext_vector_type(8)));
typedef float f32x4 __attribute__((ext_vector_type(4)));

__device__ __forceinline__ unsigned short f2bf(float f) {
    unsigned int u = __builtin_bit_cast(unsigned int, f);
    u += 0x7FFF + ((u >> 16) & 1);  // round-to-nearest-even
    return (unsigned short)(u >> 16);
}
__device__ __forceinline__ float bf2f(unsigned short h) {
    unsigned int u = ((unsigned int)h) << 16;
    return __builtin_bit_cast(float, u);
}
__device__ __forceinline__ void gload16(const void* g, void* l) {
    __builtin_amdgcn_global_load_lds(
        (const __attribute__((address_space(1))) unsigned int*)g,
        (__attribute__((address_space(3))) unsigned int*)l, 16, 0, 0);
}

// ---------------- edge dtype detection ----------------
__global__ void detect_kernel(const int* __restrict__ ei32, int* __restrict__ flag) {
    __shared__ int red[256];
    int tid = threadIdx.x;
    int o = 0;
    for (int i = tid; i < 4096; i += 256) o |= ei32[2 * i + 1];
    red[tid] = o;
    __syncthreads();
    for (int s = 128; s > 0; s >>= 1) {
        if (tid < s) red[tid] |= red[tid + s];
        __syncthreads();
    }
    if (tid == 0) *flag = (red[0] == 0) ? 1 : 0;
}

__device__ __forceinline__ int load_edge(const void* ei, int is64, long long idx) {
    return is64 ? (int)((const long long*)ei)[idx] : ((const int*)ei)[idx];
}

// ---------------- CSR build ----------------
__global__ void hist_kernel(const void* __restrict__ ei, const int* __restrict__ flag,
                            int* __restrict__ cnt, int E) {
    int e = blockIdx.x * blockDim.x + threadIdx.x;
    if (e >= E) return;
    int is64 = *flag;
    int dst = load_edge(ei, is64, (long long)E + e);
    atomicAdd(&cnt[dst], 1);
}

// pass 1: block b reduces cnt[b*1024 .. b*1024+1023] -> bsum[b]
__global__ void scan_part(const int* __restrict__ cnt, int* __restrict__ bsum, int n) {
    __shared__ int s[256];
    const int tid = threadIdx.x;
    const int i0 = blockIdx.x * 1024 + tid * 4;
    int sum = 0;
#pragma unroll
    for (int j = 0; j < 4; ++j) {
        int i = i0 + j;
        if (i < n) sum += cnt[i];
    }
    s[tid] = sum;
    __syncthreads();
    for (int o = 128; o > 0; o >>= 1) {
        if (tid < o) s[tid] += s[tid + o];
        __syncthreads();
    }
    if (tid == 0) bsum[blockIdx.x] = s[0];
}

// pass 2: one wave turns bsum[] (nb <= 64) into its exclusive scan; off[n] = total
__global__ void scan_top(int* __restrict__ bsum, int* __restrict__ off, int nb, int n) {
    const int lane = threadIdx.x & 63;
    int mine = (lane < nb) ? bsum[lane] : 0;
    int v = mine;
#pragma unroll
    for (int o = 1; o < 64; o <<= 1) {
        int t = __shfl_up(v, o, 64);
        if (lane >= o) v += t;
    }
    if (lane < nb) bsum[lane] = v - mine;  // exclusive prefix
    if (lane == 63) off[n] = v;            // grand total
}

// pass 3: block b scans its 1024 counts with base bsum[b]; writes off/pos
__global__ void scan_fin(const int* __restrict__ cnt, const int* __restrict__ bsum,
                         int* __restrict__ off, int* __restrict__ pos, int n) {
    __shared__ int s[256];
    const int tid = threadIdx.x;
    const int i0 = blockIdx.x * 1024 + tid * 4;
    int v[4];
    int sum = 0;
#pragma unroll
    for (int j = 0; j < 4; ++j) {
        int i = i0 + j;
        v[j] = (i < n) ? cnt[i] : 0;
        sum += v[j];
    }
    s[tid] = sum;
    __syncthreads();
    for (int o = 1; o < 256; o <<= 1) {
        int t = 0;
        if (tid >= o) t = s[tid - o];
        __syncthreads();
        s[tid] += t;
        __syncthreads();
    }
    int run = bsum[blockIdx.x] + s[tid] - sum;  // exclusive within grid
#pragma unroll
    for (int j = 0; j < 4; ++j) {
        int i = i0 + j;
        if (i < n) {
            off[i] = run;
            pos[i] = run;
            run += v[j];
        }
    }
}

__global__ void fill_kernel(const void* __restrict__ ei, const int* __restrict__ flag,
                            int* __restrict__ pos, int* __restrict__ adj, int E) {
    int e = blockIdx.x * blockDim.x + threadIdx.x;
    if (e >= E) return;
    int is64 = *flag;
    int src = load_edge(ei, is64, e);
    int dst = load_edge(ei, is64, (long long)E + e);
    int p = atomicAdd(&pos[dst], 1);
    adj[p] = src;
}

// ---------------- f32 -> bf16 convert ----------------
__global__ void cvt_bf16(const float* __restrict__ in, unsigned short* __restrict__ out, int n4) {
    int i = blockIdx.x * blockDim.x + threadIdx.x;
    if (i >= n4) return;
    float4 v = ((const float4*)in)[i];
    uint2 o;
    o.x = (unsigned int)f2bf(v.x) | ((unsigned int)f2bf(v.y) << 16);
    o.y = (unsigned int)f2bf(v.z) | ((unsigned int)f2bf(v.w) << 16);
    ((uint2*)out)[i] = o;
}

// ---------------- weight prep: Wt[c][k] = bf16([Wl; Wr][k][c]) ----------------
__global__ void prep_w(const float* __restrict__ Wl, const float* __restrict__ Wr,
                       unsigned short* __restrict__ Wt, int KH) {
    int c = blockIdx.x;  // 0..255
    int KC = 2 * KH;
    for (int k = threadIdx.x; k < KC; k += blockDim.x) {
        float v = (k < KH) ? Wl[(size_t)k * 256 + c] : Wr[(size_t)(k - KH) * 256 + c];
        Wt[(size_t)c * KC + k] = f2bf(v);
    }
}

// ---------------- mean aggregation, bf16 in/out, one wave per node ----------------
// Edge loop unrolled x4 with independent accumulators -> 4 row-gathers in flight (MLP=4).
template <int VPL>  // values per lane; F = 64*VPL
__global__ void agg_bf(const unsigned short* __restrict__ feat, const int* __restrict__ off,
                       const int* __restrict__ adj, unsigned short* __restrict__ out, int n) {
    int node = blockIdx.x * 4 + (threadIdx.x >> 6);
    if (node >= n) return;
    const int lane = threadIdx.x & 63;
    constexpr int F = 64 * VPL;
    const int s = off[node], e = off[node + 1];

    float a0[VPL] = {}, a1[VPL] = {}, a2[VPL] = {}, a3[VPL] = {};

    auto addrow = [&](float* acc, int src) {
        const unsigned short* p = feat + (size_t)src * F + lane * VPL;
        if constexpr (VPL == 2) {
            unsigned int v = *(const unsigned int*)p;
            acc[0] += bf2f((unsigned short)(v & 0xffff));
            acc[1] += bf2f((unsigned short)(v >> 16));
        } else {
            uint2 v = *(const uint2*)p;
            acc[0] += bf2f((unsigned short)(v.x & 0xffff));
            acc[1] += bf2f((unsigned short)(v.x >> 16));
            acc[2] += bf2f((unsigned short)(v.y & 0xffff));
            acc[3] += bf2f((unsigned short)(v.y >> 16));
        }
    };

    int j = s;
    for (; j + 4 <= e; j += 4) {
        int i0 = adj[j], i1 = adj[j + 1], i2 = adj[j + 2], i3 = adj[j + 3];
        addrow(a0, i0);
        addrow(a1, i1);
        addrow(a2, i2);
        addrow(a3, i3);
    }
    // tail (<=3), still independent accumulators
    {
        int rem = e - j;
        if (rem > 0) addrow(a0, adj[j]);
        if (rem > 1) addrow(a1, adj[j + 1]);
        if (rem > 2) addrow(a2, adj[j + 2]);
    }

    int deg = e - s;
    float inv = 1.0f / (float)(deg > 0 ? deg : 1);
#pragma unroll
    for (int k = 0; k < VPL; ++k) a0[k] = (a0[k] + a1[k] + a2[k] + a3[k]) * inv;

    if constexpr (VPL == 2) {
        unsigned int o = (unsigned int)f2bf(a0[0]) | ((unsigned int)f2bf(a0[1]) << 16);
        *(unsigned int*)(out + (size_t)node * F + lane * 2) = o;
    } else {
        uint2 o;
        o.x = (unsigned int)f2bf(a0[0]) | ((unsigned int)f2bf(a0[1]) << 16);
        o.y = (unsigned int)f2bf(a0[2]) | ((unsigned int)f2bf(a0[3]) << 16);
        *(uint2*)(out + (size_t)node * F + lane * 4) = o;
    }
}

// ---------------- fused SAGE MFMA GEMM ----------------
// C[64 x 256] per block = [agg | xin](64 x 2KH) @ Wt^T, 4 waves, wave w owns cols [64w,64w+64).
// A staged via global_load_lds into [kgroup][row][8] (linear per-lane), double-buffered.
// Epilogue: +bias, L2-normalize rows (shfl + LDS cross-wave), optional BN+ReLU, store.
template <int KH, bool L0>
__global__ __launch_bounds__(256, 2) void sage_mfma(
    const unsigned short* __restrict__ Aagg, const unsigned short* __restrict__ Axin,
    const unsigned short* __restrict__ Wt, const float* __restrict__ bl,
    const float* __restrict__ bng, const float* __restrict__ bnb,
    const float* __restrict__ bnm, const float* __restrict__ bnv,
    unsigned short* __restrict__ hout, float* __restrict__ fout, int n) {
    constexpr int KC = 2 * KH;
    constexpr int NSTEP = KC / 32;
    __shared__ __align__(16) unsigned short a_sh[2][4][64][8];  // [buf][kgrp][row][8] = 8KB
    __shared__ float red[4][64];
    __shared__ float inv_sh[64];

    const int tid = threadIdx.x;
    const int w = tid >> 6;
    const int l = tid & 63;
    const int g = l >> 4;
    const int li = l & 15;
    const int row0 = blockIdx.x * 64;
    int srow = row0 + l;
    if (srow >= n) srow = n - 1;

    f32x4 acc[4][4];
#pragma unroll
    for (int m = 0; m < 4; ++m)
#pragma unroll
        for (int nn = 0; nn < 4; ++nn) acc[m][nn] = (f32x4)(0.0f);

    auto stage = [&](int buf, int t) {
        const int k0 = t * 32;
        const unsigned short* srcm = (k0 < KH) ? Aagg : Axin;
        const int kk = (k0 < KH) ? k0 : k0 - KH;
        const unsigned short* gp = srcm + (size_t)srow * KH + kk + w * 8;
        gload16(gp, &a_sh[buf][w][0][0]);  // lane i -> a_sh[buf][w][i][0..7]
    };

    stage(0, 0);
    __syncthreads();  // vmcnt(0) drain + barrier: buf0 ready

    int cur = 0;
    for (int ks = 0; ks < NSTEP; ++ks) {
        if (ks + 1 < NSTEP) stage(cur ^ 1, ks + 1);  // prefetch in flight during compute
        const int k0 = ks * 32;
        bf16x8 bfr[4];
#pragma unroll
        for (int nn = 0; nn < 4; ++nn) {
            const unsigned short* bp = Wt + (size_t)(w * 64 + nn * 16 + li) * KC + k0 + 8 * g;
            bfr[nn] = __builtin_bit_cast(bf16x8, *(const uint4*)bp);
        }
        bf16x8 afr[4];
#pragma unroll
        for (int m = 0; m < 4; ++m)
            afr[m] = __builtin_bit_cast(bf16x8, *(const uint4*)&a_sh[cur][g][16 * m + li][0]);
#pragma unroll
        for (int nn = 0; nn < 4; ++nn)
#pragma unroll
            for (int m = 0; m < 4; ++m)
                acc[m][nn] = __builtin_amdgcn_mfma_f32_16x16x32_bf16(afr[m], bfr[nn], acc[m][nn], 0, 0, 0);
        __syncthreads();  // drains prefetch vmcnt + guards buffer swap
        cur ^= 1;
    }

    // bias
    float bv[4];
#pragma unroll
    for (int nn = 0; nn < 4; ++nn) bv[nn] = bl[w * 64 + nn * 16 + li];
#pragma unroll
    for (int m = 0; m < 4; ++m)
#pragma unroll
        for (int nn = 0; nn < 4; ++nn)
#pragma unroll
            for (int r = 0; r < 4; ++r) acc[m][nn][r] += bv[nn];

    // row sum-of-squares: reduce over this wave's 64 cols (16-lane group shuffle)
    float ssp[4][4];
#pragma unroll
    for (int m = 0; m < 4; ++m)
#pragma unroll
        for (int r = 0; r < 4; ++r) {
            float s = 0.f;
#pragma unroll
            for (int nn = 0; nn < 4; ++nn) s += acc[m][nn][r] * acc[m][nn][r];
#pragma unroll
            for (int mk = 1; mk < 16; mk <<= 1) s += __shfl_xor(s, mk, 64);
            ssp[m][r] = s;
        }
    if (li == 0) {
#pragma unroll
        for (int m = 0; m < 4; ++m)
#pragma unroll
            for (int r = 0; r < 4; ++r) red[w][16 * m + 4 * g + r] = ssp[m][r];
    }
    __syncthreads();
    if (tid < 64) {
        float tot = red[0][tid] + red[1][tid] + red[2][tid] + red[3][tid];
        inv_sh[tid] = 1.0f / fmaxf(sqrtf(tot), 1e-12f);
    }
    __syncthreads();

    float sc[4], sh[4];
    if (L0) {
#pragma unroll
        for (int nn = 0; nn < 4; ++nn) {
            int c = w * 64 + nn * 16 + li;
            float s = bng[c] * rsqrtf(bnv[c] + 1e-5f);
            sc[nn] = s;
            sh[nn] = bnb[c] - bnm[c] * s;
        }
    }
#pragma unroll
    for (int m = 0; m < 4; ++m) {
#pragma unroll
        for (int r = 0; r < 4; ++r) {
            int rl = 16 * m + 4 * g + r;
            int row = row0 + rl;
            if (row < n) {
                float inv = inv_sh[rl];
#pragma unroll
                for (int nn = 0; nn < 4; ++nn) {
                    int c = w * 64 + nn * 16 + li;
                    float v = acc[m][nn][r] * inv;
                    if (L0) {
                        v = fmaxf(v * sc[nn] + sh[nn], 0.f);
                        hout[(size_t)row * 256 + c] = f2bf(v);
                    } else {
                        fout[(size_t)row * 256 + c] = v;
                    }
                }
            }
        }
    }
}

// ---------------- launch ----------------
extern "C" void kernel_launch(void* const* d_in, const int* in_sizes, int n_in,
                              void* d_out, int out_size, void* d_ws, size_t ws_size,
                              hipStream_t stream) {
    const float* x   = (const float*)d_in[0];
    const void*  ei  = d_in[1];
    const float* Wl0 = (const float*)d_in[2];
    const float* bl0 = (const float*)d_in[3];
    const float* Wr0 = (const float*)d_in[4];
    const float* Wl1 = (const float*)d_in[5];
    const float* bl1 = (const float*)d_in[6];
    const float* Wr1 = (const float*)d_in[7];
    const float* bng = (const float*)d_in[8];
    const float* bnb = (const float*)d_in[9];
    const float* bnm = (const float*)d_in[10];
    const float* bnv = (const float*)d_in[11];
    float* out = (float*)d_out;

    const int N = NN;
    const int E = in_sizes[1] / 2;
    const int NB = (N + 1023) / 1024;  // 49 scan blocks

    char* wsp = (char*)d_ws;
    size_t o = 0;
    auto carve = [&](size_t bytes) {
        void* p = wsp + o;
        o = (o + bytes + 255) & ~(size_t)255;
        return p;
    };
    int* flag = (int*)carve(4);
    int* cnt  = (int*)carve((size_t)N * 4);
    int* off  = (int*)carve((size_t)(N + 1) * 4);
    int* pos  = (int*)carve((size_t)N * 4);
    int* bsum = (int*)carve((size_t)NB * 4);
    int* adj  = (int*)carve((size_t)E * 4);
    unsigned short* xbf  = (unsigned short*)carve((size_t)N * 128 * 2);
    unsigned short* agg0 = (unsigned short*)carve((size_t)N * 128 * 2);
    unsigned short* agg1 = xbf;  // reuse xbf region (dead after layer 0)
    unsigned short* hbf  = (unsigned short*)carve((size_t)N * 256 * 2);
    unsigned short* Wt0  = (unsigned short*)carve((size_t)256 * 256 * 2);
    unsigned short* Wt1  = (unsigned short*)carve((size_t)256 * 512 * 2);

    hipMemsetAsync(d_ws, 0, 256 + (size_t)N * 4, stream);

    detect_kernel<<<1, 256, 0, stream>>>((const int*)ei, flag);
    hist_kernel<<<(E + 255) / 256, 256, 0, stream>>>(ei, flag, cnt, E);
    scan_part<<<NB, 256, 0, stream>>>(cnt, bsum, N);
    scan_top<<<1, 64, 0, stream>>>(bsum, off, NB, N);
    scan_fin<<<NB, 256, 0, stream>>>(cnt, bsum, off, pos, N);
    fill_kernel<<<(E + 255) / 256, 256, 0, stream>>>(ei, flag, pos, adj, E);

    cvt_bf16<<<(N * 128 / 4 + 255) / 256, 256, 0, stream>>>(x, xbf, N * 128 / 4);
    prep_w<<<256, 256, 0, stream>>>(Wl0, Wr0, Wt0, 128);
    prep_w<<<256, 256, 0, stream>>>(Wl1, Wr1, Wt1, 256);

    agg_bf<2><<<(N + 3) / 4, 256, 0, stream>>>(xbf, off, adj, agg0, N);
    sage_mfma<128, true><<<(N + 63) / 64, 256, 0, stream>>>(
        agg0, xbf, Wt0, bl0, bng, bnb, bnm, bnv, hbf, nullptr, N);

    agg_bf<4><<<(N + 3) / 4, 256, 0, stream>>>(hbf, off, adj, agg1, N);
    sage_mfma<256, false><<<(N + 63) / 64, 256, 0, stream>>>(
        agg1, hbf, Wt1, bl1, bng, bnb, bnm, bnv, nullptr, out, N);
}

// Round 5
// 249.375 us; speedup vs baseline: 4.0231x; 1.0122x over previous
//
#include <hip/hip_runtime.h>

#define NN 50000

typedef __bf16 bf16x8 __attribute__((ext_vector_type(8)));
typedef float f32x4 __attribute__((ext_vector_type(4)));

__device__ __forceinline__ unsigned short f2bf(float f) {
    unsigned int u = __builtin_bit_cast(unsigned int, f);
    u += 0x7FFF + ((u >> 16) & 1);  // round-to-nearest-even
    return (unsigned short)(u >> 16);
}
__device__ __forceinline__ float bf2f(unsigned short h) {
    unsigned int u = ((unsigned int)h) << 16;
    return __builtin_bit_cast(float, u);
}
__device__ __forceinline__ void gload16(const void* g, void* l) {
    __builtin_amdgcn_global_load_lds(
        (const __attribute__((address_space(1))) unsigned int*)g,
        (__attribute__((address_space(3))) unsigned int*)l, 16, 0, 0);
}

// ---------------- edge dtype detection ----------------
__global__ void detect_kernel(const int* __restrict__ ei32, int* __restrict__ flag) {
    __shared__ int red[256];
    int tid = threadIdx.x;
    int o = 0;
    for (int i = tid; i < 4096; i += 256) o |= ei32[2 * i + 1];
    red[tid] = o;
    __syncthreads();
    for (int s = 128; s > 0; s >>= 1) {
        if (tid < s) red[tid] |= red[tid + s];
        __syncthreads();
    }
    if (tid == 0) *flag = (red[0] == 0) ? 1 : 0;
}

__device__ __forceinline__ int load_edge(const void* ei, int is64, long long idx) {
    return is64 ? (int)((const long long*)ei)[idx] : ((const int*)ei)[idx];
}

// ---------------- CSR build ----------------
__global__ void hist_kernel(const void* __restrict__ ei, const int* __restrict__ flag,
                            int* __restrict__ cnt, int E) {
    int e = blockIdx.x * blockDim.x + threadIdx.x;
    if (e >= E) return;
    int is64 = *flag;
    int dst = load_edge(ei, is64, (long long)E + e);
    atomicAdd(&cnt[dst], 1);
}

// pass 1: block b reduces cnt[b*1024 .. b*1024+1023] -> bsum[b]
__global__ void scan_part(const int* __restrict__ cnt, int* __restrict__ bsum, int n) {
    __shared__ int s[256];
    const int tid = threadIdx.x;
    const int i0 = blockIdx.x * 1024 + tid * 4;
    int sum = 0;
#pragma unroll
    for (int j = 0; j < 4; ++j) {
        int i = i0 + j;
        if (i < n) sum += cnt[i];
    }
    s[tid] = sum;
    __syncthreads();
    for (int o = 128; o > 0; o >>= 1) {
        if (tid < o) s[tid] += s[tid + o];
        __syncthreads();
    }
    if (tid == 0) bsum[blockIdx.x] = s[0];
}

// pass 2: one wave turns bsum[] (nb <= 64) into its exclusive scan; off[n] = total
__global__ void scan_top(int* __restrict__ bsum, int* __restrict__ off, int nb, int n) {
    const int lane = threadIdx.x & 63;
    int mine = (lane < nb) ? bsum[lane] : 0;
    int v = mine;
#pragma unroll
    for (int o = 1; o < 64; o <<= 1) {
        int t = __shfl_up(v, o, 64);
        if (lane >= o) v += t;
    }
    if (lane < nb) bsum[lane] = v - mine;  // exclusive prefix
    if (lane == 63) off[n] = v;            // grand total
}

// pass 3: block b scans its 1024 counts with base bsum[b]; writes off/pos
__global__ void scan_fin(const int* __restrict__ cnt, const int* __restrict__ bsum,
                         int* __restrict__ off, int* __restrict__ pos, int n) {
    __shared__ int s[256];
    const int tid = threadIdx.x;
    const int i0 = blockIdx.x * 1024 + tid * 4;
    int v[4];
    int sum = 0;
#pragma unroll
    for (int j = 0; j < 4; ++j) {
        int i = i0 + j;
        v[j] = (i < n) ? cnt[i] : 0;
        sum += v[j];
    }
    s[tid] = sum;
    __syncthreads();
    for (int o = 1; o < 256; o <<= 1) {
        int t = 0;
        if (tid >= o) t = s[tid - o];
        __syncthreads();
        s[tid] += t;
        __syncthreads();
    }
    int run = bsum[blockIdx.x] + s[tid] - sum;  // exclusive within grid
#pragma unroll
    for (int j = 0; j < 4; ++j) {
        int i = i0 + j;
        if (i < n) {
            off[i] = run;
            pos[i] = run;
            run += v[j];
        }
    }
}

__global__ void fill_kernel(const void* __restrict__ ei, const int* __restrict__ flag,
                            int* __restrict__ pos, int* __restrict__ adj, int E) {
    int e = blockIdx.x * blockDim.x + threadIdx.x;
    if (e >= E) return;
    int is64 = *flag;
    int src = load_edge(ei, is64, e);
    int dst = load_edge(ei, is64, (long long)E + e);
    int p = atomicAdd(&pos[dst], 1);
    adj[p] = src;
}

// ---------------- f32 -> bf16 convert ----------------
__global__ void cvt_bf16(const float* __restrict__ in, unsigned short* __restrict__ out, int n4) {
    int i = blockIdx.x * blockDim.x + threadIdx.x;
    if (i >= n4) return;
    float4 v = ((const float4*)in)[i];
    uint2 o;
    o.x = (unsigned int)f2bf(v.x) | ((unsigned int)f2bf(v.y) << 16);
    o.y = (unsigned int)f2bf(v.z) | ((unsigned int)f2bf(v.w) << 16);
    ((uint2*)out)[i] = o;
}

// ---------------- weight prep: Wt[c][k] = bf16([Wl; Wr][k][c]) ----------------
__global__ void prep_w(const float* __restrict__ Wl, const float* __restrict__ Wr,
                       unsigned short* __restrict__ Wt, int KH) {
    int c = blockIdx.x;  // 0..255
    int KC = 2 * KH;
    for (int k = threadIdx.x; k < KC; k += blockDim.x) {
        float v = (k < KH) ? Wl[(size_t)k * 256 + c] : Wr[(size_t)(k - KH) * 256 + c];
        Wt[(size_t)c * KC + k] = f2bf(v);
    }
}

// ---------------- mean aggregation, bf16 in/out, one wave per node ----------------
// Edge loop unrolled x4 with independent accumulators -> 4 row-gathers in flight (MLP=4).
template <int VPL>  // values per lane; F = 64*VPL
__global__ void agg_bf(const unsigned short* __restrict__ feat, const int* __restrict__ off,
                       const int* __restrict__ adj, unsigned short* __restrict__ out, int n) {
    int node = blockIdx.x * 4 + (threadIdx.x >> 6);
    if (node >= n) return;
    const int lane = threadIdx.x & 63;
    constexpr int F = 64 * VPL;
    const int s = off[node], e = off[node + 1];

    float a0[VPL] = {}, a1[VPL] = {}, a2[VPL] = {}, a3[VPL] = {};

    auto addrow = [&](float* acc, int src) {
        const unsigned short* p = feat + (size_t)src * F + lane * VPL;
        if constexpr (VPL == 2) {
            unsigned int v = *(const unsigned int*)p;
            acc[0] += bf2f((unsigned short)(v & 0xffff));
            acc[1] += bf2f((unsigned short)(v >> 16));
        } else {
            uint2 v = *(const uint2*)p;
            acc[0] += bf2f((unsigned short)(v.x & 0xffff));
            acc[1] += bf2f((unsigned short)(v.x >> 16));
            acc[2] += bf2f((unsigned short)(v.y & 0xffff));
            acc[3] += bf2f((unsigned short)(v.y >> 16));
        }
    };

    int j = s;
    for (; j + 4 <= e; j += 4) {
        int i0 = adj[j], i1 = adj[j + 1], i2 = adj[j + 2], i3 = adj[j + 3];
        addrow(a0, i0);
        addrow(a1, i1);
        addrow(a2, i2);
        addrow(a3, i3);
    }
    // tail (<=3), still independent accumulators
    {
        int rem = e - j;
        if (rem > 0) addrow(a0, adj[j]);
        if (rem > 1) addrow(a1, adj[j + 1]);
        if (rem > 2) addrow(a2, adj[j + 2]);
    }

    int deg = e - s;
    float inv = 1.0f / (float)(deg > 0 ? deg : 1);
#pragma unroll
    for (int k = 0; k < VPL; ++k) a0[k] = (a0[k] + a1[k] + a2[k] + a3[k]) * inv;

    if constexpr (VPL == 2) {
        unsigned int o = (unsigned int)f2bf(a0[0]) | ((unsigned int)f2bf(a0[1]) << 16);
        *(unsigned int*)(out + (size_t)node * F + lane * 2) = o;
    } else {
        uint2 o;
        o.x = (unsigned int)f2bf(a0[0]) | ((unsigned int)f2bf(a0[1]) << 16);
        o.y = (unsigned int)f2bf(a0[2]) | ((unsigned int)f2bf(a0[3]) << 16);
        *(uint2*)(out + (size_t)node * F + lane * 4) = o;
    }
}

// ---------------- fused SAGE MFMA GEMM (whole-K LDS preload, barrier-free K-loop) ----
// C[64 x 256] per block = [agg | xin](64 x 2KH) @ Wt^T, 4 waves, wave w owns cols [64w,64w+64).
// ALL of A (64 rows x KC) staged into LDS up front via NSTEP global_load_lds per wave
// (16-deep MLP), ONE barrier, then the K-loop has no barriers: ds_read + L2-resident
// B loads + MFMA, freely software-pipelined by the compiler.
// Reduction scratch aliases the dead A-panel LDS after the loop.
template <int KH, bool L0>
__global__ __launch_bounds__(256, 2) void sage_mfma(
    const unsigned short* __restrict__ Aagg, const unsigned short* __restrict__ Axin,
    const unsigned short* __restrict__ Wt, const float* __restrict__ bl,
    const float* __restrict__ bng, const float* __restrict__ bnb,
    const float* __restrict__ bnm, const float* __restrict__ bnv,
    unsigned short* __restrict__ hout, float* __restrict__ fout, int n) {
    constexpr int KC = 2 * KH;
    constexpr int NSTEP = KC / 32;
    // [step][kgrp][row][8] : L1 = 64KB exactly, L0 = 32KB
    __shared__ __align__(16) unsigned short a_sh[NSTEP][4][64][8];

    const int tid = threadIdx.x;
    const int w = tid >> 6;
    const int l = tid & 63;
    const int g = l >> 4;
    const int li = l & 15;
    const int row0 = blockIdx.x * 64;
    int srow = row0 + l;
    if (srow >= n) srow = n - 1;

    f32x4 acc[4][4];
#pragma unroll
    for (int m = 0; m < 4; ++m)
#pragma unroll
        for (int nn = 0; nn < 4; ++nn) acc[m][nn] = (f32x4)(0.0f);

    // stage the ENTIRE A panel: wave w covers k-slice [t*32 + w*8, +8) for each step t
#pragma unroll
    for (int t = 0; t < NSTEP; ++t) {
        const int k0 = t * 32;
        const unsigned short* srcm = (k0 < KH) ? Aagg : Axin;
        const int kk = (k0 < KH) ? k0 : k0 - KH;
        const unsigned short* gp = srcm + (size_t)srow * KH + kk + w * 8;
        gload16(gp, &a_sh[t][w][0][0]);  // lane i -> a_sh[t][w][i][0..7]
    }
    __syncthreads();  // single drain: all NSTEP stages complete

#pragma unroll 4
    for (int ks = 0; ks < NSTEP; ++ks) {
        const int k0 = ks * 32;
        bf16x8 bfr[4];
#pragma unroll
        for (int nn = 0; nn < 4; ++nn) {
            const unsigned short* bp = Wt + (size_t)(w * 64 + nn * 16 + li) * KC + k0 + 8 * g;
            bfr[nn] = __builtin_bit_cast(bf16x8, *(const uint4*)bp);
        }
        bf16x8 afr[4];
#pragma unroll
        for (int m = 0; m < 4; ++m)
            afr[m] = __builtin_bit_cast(bf16x8, *(const uint4*)&a_sh[ks][g][16 * m + li][0]);
#pragma unroll
        for (int nn = 0; nn < 4; ++nn)
#pragma unroll
            for (int m = 0; m < 4; ++m)
                acc[m][nn] = __builtin_amdgcn_mfma_f32_16x16x32_bf16(afr[m], bfr[nn], acc[m][nn], 0, 0, 0);
    }

    // bias
    float bv[4];
#pragma unroll
    for (int nn = 0; nn < 4; ++nn) bv[nn] = bl[w * 64 + nn * 16 + li];
#pragma unroll
    for (int m = 0; m < 4; ++m)
#pragma unroll
        for (int nn = 0; nn < 4; ++nn)
#pragma unroll
            for (int r = 0; r < 4; ++r) acc[m][nn][r] += bv[nn];

    // row sum-of-squares: reduce over this wave's 64 cols (16-lane group shuffle)
    float ssp[4][4];
#pragma unroll
    for (int m = 0; m < 4; ++m)
#pragma unroll
        for (int r = 0; r < 4; ++r) {
            float s = 0.f;
#pragma unroll
            for (int nn = 0; nn < 4; ++nn) s += acc[m][nn][r] * acc[m][nn][r];
#pragma unroll
            for (int mk = 1; mk < 16; mk <<= 1) s += __shfl_xor(s, mk, 64);
            ssp[m][r] = s;
        }

    __syncthreads();  // A panel dead; reuse LDS for cross-wave reduction
    float* redp = (float*)&a_sh[0][0][0][0];  // [4][64] partials then [64] inv

    if (li == 0) {
#pragma unroll
        for (int m = 0; m < 4; ++m)
#pragma unroll
            for (int r = 0; r < 4; ++r) redp[w * 64 + 16 * m + 4 * g + r] = ssp[m][r];
    }
    __syncthreads();
    if (tid < 64) {
        float tot = redp[tid] + redp[64 + tid] + redp[128 + tid] + redp[192 + tid];
        redp[256 + tid] = 1.0f / fmaxf(sqrtf(tot), 1e-12f);
    }
    __syncthreads();

    float sc[4], sh[4];
    if (L0) {
#pragma unroll
        for (int nn = 0; nn < 4; ++nn) {
            int c = w * 64 + nn * 16 + li;
            float s = bng[c] * rsqrtf(bnv[c] + 1e-5f);
            sc[nn] = s;
            sh[nn] = bnb[c] - bnm[c] * s;
        }
    }
#pragma unroll
    for (int m = 0; m < 4; ++m) {
#pragma unroll
        for (int r = 0; r < 4; ++r) {
            int rl = 16 * m + 4 * g + r;
            int row = row0 + rl;
            if (row < n) {
                float inv = redp[256 + rl];
#pragma unroll
                for (int nn = 0; nn < 4; ++nn) {
                    int c = w * 64 + nn * 16 + li;
                    float v = acc[m][nn][r] * inv;
                    if (L0) {
                        v = fmaxf(v * sc[nn] + sh[nn], 0.f);
                        hout[(size_t)row * 256 + c] = f2bf(v);
                    } else {
                        fout[(size_t)row * 256 + c] = v;
                    }
                }
            }
        }
    }
}

// ---------------- launch ----------------
extern "C" void kernel_launch(void* const* d_in, const int* in_sizes, int n_in,
                              void* d_out, int out_size, void* d_ws, size_t ws_size,
                              hipStream_t stream) {
    const float* x   = (const float*)d_in[0];
    const void*  ei  = d_in[1];
    const float* Wl0 = (const float*)d_in[2];
    const float* bl0 = (const float*)d_in[3];
    const float* Wr0 = (const float*)d_in[4];
    const float* Wl1 = (const float*)d_in[5];
    const float* bl1 = (const float*)d_in[6];
    const float* Wr1 = (const float*)d_in[7];
    const float* bng = (const float*)d_in[8];
    const float* bnb = (const float*)d_in[9];
    const float* bnm = (const float*)d_in[10];
    const float* bnv = (const float*)d_in[11];
    float* out = (float*)d_out;

    const int N = NN;
    const int E = in_sizes[1] / 2;
    const int NB = (N + 1023) / 1024;  // 49 scan blocks

    char* wsp = (char*)d_ws;
    size_t o = 0;
    auto carve = [&](size_t bytes) {
        void* p = wsp + o;
        o = (o + bytes + 255) & ~(size_t)255;
        return p;
    };
    int* flag = (int*)carve(4);
    int* cnt  = (int*)carve((size_t)N * 4);
    int* off  = (int*)carve((size_t)(N + 1) * 4);
    int* pos  = (int*)carve((size_t)N * 4);
    int* bsum = (int*)carve((size_t)NB * 4);
    int* adj  = (int*)carve((size_t)E * 4);
    unsigned short* xbf  = (unsigned short*)carve((size_t)N * 128 * 2);
    unsigned short* agg0 = (unsigned short*)carve((size_t)N * 128 * 2);
    unsigned short* agg1 = xbf;  // reuse xbf region (dead after layer 0)
    unsigned short* hbf  = (unsigned short*)carve((size_t)N * 256 * 2);
    unsigned short* Wt0  = (unsigned short*)carve((size_t)256 * 256 * 2);
    unsigned short* Wt1  = (unsigned short*)carve((size_t)256 * 512 * 2);

    hipMemsetAsync(d_ws, 0, 256 + (size_t)N * 4, stream);

    detect_kernel<<<1, 256, 0, stream>>>((const int*)ei, flag);
    hist_kernel<<<(E + 255) / 256, 256, 0, stream>>>(ei, flag, cnt, E);
    scan_part<<<NB, 256, 0, stream>>>(cnt, bsum, N);
    scan_top<<<1, 64, 0, stream>>>(bsum, off, NB, N);
    scan_fin<<<NB, 256, 0, stream>>>(cnt, bsum, off, pos, N);
    fill_kernel<<<(E + 255) / 256, 256, 0, stream>>>(ei, flag, pos, adj, E);

    cvt_bf16<<<(N * 128 / 4 + 255) / 256, 256, 0, stream>>>(x, xbf, N * 128 / 4);
    prep_w<<<256, 256, 0, stream>>>(Wl0, Wr0, Wt0, 128);
    prep_w<<<256, 256, 0, stream>>>(Wl1, Wr1, Wt1, 256);

    agg_bf<2><<<(N + 3) / 4, 256, 0, stream>>>(xbf, off, adj, agg0, N);
    sage_mfma<128, true><<<(N + 63) / 64, 256, 0, stream>>>(
        agg0, xbf, Wt0, bl0, bng, bnb, bnm, bnv, hbf, nullptr, N);

    agg_bf<4><<<(N + 3) / 4, 256, 0, stream>>>(hbf, off, adj, agg1, N);
    sage_mfma<256, false><<<(N + 63) / 64, 256, 0, stream>>>(
        agg1, hbf, Wt1, bl1, bng, bnb, bnm, bnv, nullptr, out, N);
}